// Round 4
// baseline (676.721 us; speedup 1.0000x reference)
//
#include <hip/hip_runtime.h>
#include <stdint.h>

#define M_DIM 4096
#define K_DIM 4096
#define N_DIM 11008

typedef _Float16 half2v __attribute__((ext_vector_type(2)));
typedef _Float16 half8  __attribute__((ext_vector_type(8)));
typedef float    f32x16 __attribute__((ext_vector_type(16)));

#define SCHED_FENCE() __builtin_amdgcn_sched_barrier(0)

// cvt_pkrtz returns __fp16x2; route through bits (clang _Float16/__fp16 mismatch).
__device__ __forceinline__ unsigned int pkrtz_bits(float a, float b) {
  typedef __fp16 fp16x2 __attribute__((ext_vector_type(2)));
  union { fp16x2 h; unsigned int u; } c;
  c.h = __builtin_amdgcn_cvt_pkrtz(a, b);
  return c.u;
}

// Pack 8 f32 (exactly-fp16-valued) into fp16, Marlin order {0,4,1,5,2,6,3,7}.
__device__ __forceinline__ half8 pack8(float4 lo, float4 hi) {
  union { unsigned int u[4]; half8 v; } r;
  r.u[0] = pkrtz_bits(lo.x, hi.x);
  r.u[1] = pkrtz_bits(lo.y, hi.y);
  r.u[2] = pkrtz_bits(lo.z, hi.z);
  r.u[3] = pkrtz_bits(lo.w, hi.w);
  return r.v;
}

// Pre-pass: X f32 [M][K] -> fp16 [M][K], k-permuted within each octet.
__global__ __launch_bounds__(256) void convert_x(const float* __restrict__ X,
                                                 _Float16* __restrict__ X16) {
  size_t g = (size_t)blockIdx.x * 256 + threadIdx.x;
  const float4* p = (const float4*)(X + g * 8);
  float4 lo = p[0], hi = p[1];
  *(half8*)(X16 + g * 8) = pack8(lo, hi);
}

// 8 nibbles -> 8 fp16 (q - (z+1)), Marlin order; zoff = half2(1025+z,1025+z).
__device__ __forceinline__ half8 unpack8(unsigned int q, half2v zoff) {
  union { unsigned int u; half2v h; } t0, t1, t2, t3;
  t0.u = (q & 0x000F000Fu) | 0x64006400u;
  t1.u = ((q >> 4) & 0x000F000Fu) | 0x64006400u;
  t2.u = ((q >> 8) & 0x000F000Fu) | 0x64006400u;
  t3.u = ((q >> 12) & 0x000F000Fu) | 0x64006400u;
  union { half2v h[4]; half8 v; } r;
  r.h[0] = t0.h - zoff;
  r.h[1] = t1.h - zoff;
  r.h[2] = t2.h - zoff;
  r.h[3] = t3.h - zoff;
  return r.v;
}

// Async global->LDS, 16B/lane. LDS dst = wave-uniform base + lane*16 (m97 pattern).
__device__ __forceinline__ void stage16(const void* g, void* l) {
  __builtin_amdgcn_global_load_lds((__attribute__((address_space(1))) unsigned int*)g,
                                   (__attribute__((address_space(3))) unsigned int*)l,
                                   16, 0, 0);
}

// r3: 8-phase-template port (m194-m201). 256x256 block, BK=64, 512 thr = 8 waves
// (2m x 4n), wave tile 128x64, MFMA 32x32x16_f16 (4mt x 2nt = 8 MFMA/phase).
// A: 3x 32KB LDS buffers, 2-stage-ahead gload_lds. B: register-direct int4,
// 2-stage-ahead, static slots q[3][4][2]. Per stage 4 phases, each:
//   {4 ds_read_b128 -> issue 1 gload_lds + 2 B loads -> barrier -> lgkm(0)
//    -> setprio(1) 8 MFMA setprio(0) -> barrier}
// ONE counted vmcnt(12) per stage (phase 3, before the last barrier): drains
// stage ks-1's 12 issues (buf/q for ks+1), leaves ks's 12 in flight. Never
// vmcnt(0) in the main loop (T4). Rationale: r0-r2 proved the 2-barrier
// structure is ceiling-bound at ~33% MfmaUtil regardless of load scheduling.
__global__ __launch_bounds__(512, 2) void gptq_gemm(
    const _Float16* __restrict__ X16,   // fp16 [M][K], Marlin octet order (d_ws)
    const int* __restrict__ QW,         // int32 [K/8][N]
    const int* __restrict__ QZ,         // int32 [1][N/8]
    const float* __restrict__ SC,       // f32 [1][N]
    float* __restrict__ OUT) {          // f32 [M][N]
  const int tid  = threadIdx.x;
  const int lane = tid & 63;
  const int wave = tid >> 6;      // 0..7
  const int wr   = wave >> 2;     // 0..1 (m row)
  const int wn   = wave & 3;      // 0..3 (n col)
  const int l32  = lane & 31;
  const int kh   = lane >> 5;     // 0..1 (k half of the MFMA fragment)
  const int bx = blockIdx.x;      // 43
  const int by = blockIdx.y;      // 16

  __shared__ __align__(16) _Float16 ldsA[3 * 16384];  // 3 x 32KB = 96 KB

  // Staging: thread t owns row m = t&255, chunk i covers octets i*2+(t>>8).
  // LDS chunk c = i*512 + t at f16 offset c*8 -> [octet:8][m:256] per buffer.
  const _Float16* gA = X16 + (size_t)(by * 256 + (tid & 255)) * K_DIM + (tid >> 8) * 8;
  _Float16* lwt = ldsA + (size_t)tid * 8;

  // B: fragment (stage ks, phase p): QW row = ks*8 + p*2 + kh, col = n.
  const int* qB = QW + (size_t)kh * N_DIM + bx * 256 + wn * 64 + l32;

  half2v zoff[2];
  float sc[2];
#pragma unroll
  for (int nt = 0; nt < 2; ++nt) {
    int n = bx * 256 + wn * 64 + nt * 32 + l32;
    int z = (QZ[n >> 3] >> ((n & 7) * 4)) & 15;
    union { unsigned int u; half2v h; } zc;
    unsigned int zb = 0x6400u + (unsigned int)(z + 1);   // fp16 bits of 1025+z
    zc.u = (zb << 16) | zb;
    zoff[nt] = zc.h;
    sc[nt] = SC[n];
  }

  f32x16 acc[4][2] = {};
  int q[3][4][2];   // [slot][phase][nt], all indices compile-time constants

  // ---- Prologue: stage 0 -> buf0/q[0]; stage 1 -> buf1/q[1] (24 VMEM, ordered).
#pragma unroll
  for (int i = 0; i < 4; ++i)
    stage16(gA + i * 16, lwt + i * 4096);
#pragma unroll
  for (int p = 0; p < 4; ++p)
#pragma unroll
    for (int nt = 0; nt < 2; ++nt)
      q[0][p][nt] = qB[(size_t)(p * 2) * N_DIM + nt * 32];
  SCHED_FENCE();
#pragma unroll
  for (int i = 0; i < 4; ++i)
    stage16(gA + 64 + i * 16, lwt + 16384 + i * 4096);
#pragma unroll
  for (int p = 0; p < 4; ++p)
#pragma unroll
    for (int nt = 0; nt < 2; ++nt)
      q[1][p][nt] = qB[(size_t)(8 + p * 2) * N_DIM + nt * 32];
  SCHED_FENCE();
  gA += 64;                 // stage-1 base; stage-top advance yields stage-2
  qB += (size_t)8 * N_DIM;
  asm volatile("s_waitcnt vmcnt(12)" ::: "memory");  // stage-0's 12 drained
  __builtin_amdgcn_s_barrier();

  // One phase. P/RB/WB compile-time. Issues (if LT62) go to buf/q slot WB
  // (stage ks+2); compute reads buf/q slot RB (stage ks).
#define PHASE(P, RB, WB, LT62, KS62)                                          \
  {                                                                           \
    const _Float16* ab = ldsA + (RB) * 16384 +                                \
        (size_t)(((P) * 2 + kh) * 256 + wr * 128 + l32) * 8;                  \
    half8 a0 = *(const half8*)(ab + 0 * 256);                                 \
    half8 a1 = *(const half8*)(ab + 1 * 256);                                 \
    half8 a2 = *(const half8*)(ab + 2 * 256);                                 \
    half8 a3 = *(const half8*)(ab + 3 * 256);                                 \
    if (LT62) {                                                               \
      stage16(gA + (P) * 16, lwt + (WB) * 16384 + (P) * 4096);                \
      q[WB][P][0] = qB[(size_t)((P) * 2) * N_DIM];                            \
      q[WB][P][1] = qB[(size_t)((P) * 2) * N_DIM + 32];                       \
      SCHED_FENCE();                                                          \
    }                                                                         \
    __builtin_amdgcn_s_barrier();                                             \
    asm volatile("s_waitcnt lgkmcnt(0)" ::: "memory");                        \
    {                                                                         \
      half8 b0 = unpack8((unsigned int)q[RB][(P)][0], zoff[0]);               \
      half8 b1 = unpack8((unsigned int)q[RB][(P)][1], zoff[1]);               \
      __builtin_amdgcn_s_setprio(1);                                          \
      acc[0][0] = __builtin_amdgcn_mfma_f32_32x32x16_f16(a0, b0, acc[0][0], 0, 0, 0); \
      acc[0][1] = __builtin_amdgcn_mfma_f32_32x32x16_f16(a0, b1, acc[0][1], 0, 0, 0); \
      acc[1][0] = __builtin_amdgcn_mfma_f32_32x32x16_f16(a1, b0, acc[1][0], 0, 0, 0); \
      acc[1][1] = __builtin_amdgcn_mfma_f32_32x32x16_f16(a1, b1, acc[1][1], 0, 0, 0); \
      acc[2][0] = __builtin_amdgcn_mfma_f32_32x32x16_f16(a2, b0, acc[2][0], 0, 0, 0); \
      acc[2][1] = __builtin_amdgcn_mfma_f32_32x32x16_f16(a2, b1, acc[2][1], 0, 0, 0); \
      acc[3][0] = __builtin_amdgcn_mfma_f32_32x32x16_f16(a3, b0, acc[3][0], 0, 0, 0); \
      acc[3][1] = __builtin_amdgcn_mfma_f32_32x32x16_f16(a3, b1, acc[3][1], 0, 0, 0); \
      __builtin_amdgcn_s_setprio(0);                                          \
    }                                                                         \
    if ((P) == 3) {                                                           \
      if (KS62) asm volatile("s_waitcnt vmcnt(0)" ::: "memory");              \
      else      asm volatile("s_waitcnt vmcnt(12)" ::: "memory");             \
    }                                                                         \
    __builtin_amdgcn_s_barrier();                                             \
  }

#define STAGE(KS, RB, WB)                                                     \
  {                                                                           \
    const int ks_ = (KS);                                                     \
    const bool lt62 = (ks_ < 62);                                             \
    const bool k62  = (ks_ == 62);                                            \
    if (lt62) { gA += 64; qB += (size_t)8 * N_DIM; }                          \
    PHASE(0, RB, WB, lt62, k62)                                               \
    PHASE(1, RB, WB, lt62, k62)                                               \
    PHASE(2, RB, WB, lt62, k62)                                               \
    PHASE(3, RB, WB, lt62, k62)                                               \
  }

  // Stages 0..62 (21 x 3, slot = ks % 3 statically).
  for (int it = 0; it < 21; ++it) {
    STAGE(it * 3 + 0, 0, 2)
    STAGE(it * 3 + 1, 1, 0)
    STAGE(it * 3 + 2, 2, 1)
  }
#undef STAGE
#undef PHASE

  // ---- Tail stage ks=63: buf0 / q[0] (staged at ks=61, drained at ks=62).
#pragma unroll
  for (int p = 0; p < 4; ++p) {
    const _Float16* ab = ldsA + (size_t)((p * 2 + kh) * 256 + wr * 128 + l32) * 8;
    half8 a0 = *(const half8*)(ab + 0 * 256);
    half8 a1 = *(const half8*)(ab + 1 * 256);
    half8 a2 = *(const half8*)(ab + 2 * 256);
    half8 a3 = *(const half8*)(ab + 3 * 256);
    half8 b0 = unpack8((unsigned int)q[0][p][0], zoff[0]);
    half8 b1 = unpack8((unsigned int)q[0][p][1], zoff[1]);
    acc[0][0] = __builtin_amdgcn_mfma_f32_32x32x16_f16(a0, b0, acc[0][0], 0, 0, 0);
    acc[0][1] = __builtin_amdgcn_mfma_f32_32x32x16_f16(a0, b1, acc[0][1], 0, 0, 0);
    acc[1][0] = __builtin_amdgcn_mfma_f32_32x32x16_f16(a1, b0, acc[1][0], 0, 0, 0);
    acc[1][1] = __builtin_amdgcn_mfma_f32_32x32x16_f16(a1, b1, acc[1][1], 0, 0, 0);
    acc[2][0] = __builtin_amdgcn_mfma_f32_32x32x16_f16(a2, b0, acc[2][0], 0, 0, 0);
    acc[2][1] = __builtin_amdgcn_mfma_f32_32x32x16_f16(a2, b1, acc[2][1], 0, 0, 0);
    acc[3][0] = __builtin_amdgcn_mfma_f32_32x32x16_f16(a3, b0, acc[3][0], 0, 0, 0);
    acc[3][1] = __builtin_amdgcn_mfma_f32_32x32x16_f16(a3, b1, acc[3][1], 0, 0, 0);
  }

  // Epilogue: 32x32 C/D layout (m74/m101): col=lane&31,
  // row=(reg&3)+8*(reg>>2)+4*(lane>>5).
#pragma unroll
  for (int mt = 0; mt < 4; ++mt) {
#pragma unroll
    for (int nt = 0; nt < 2; ++nt) {
      const int n = bx * 256 + wn * 64 + nt * 32 + l32;
      const float s = sc[nt];
      const size_t mb = (size_t)(by * 256 + wr * 128 + mt * 32 + kh * 4);
#pragma unroll
      for (int r = 0; r < 16; ++r) {
        const int row = (r & 3) + 8 * (r >> 2);
        OUT[(mb + row) * N_DIM + n] = acc[mt][nt][r] * s;
      }
    }
  }
}

extern "C" void kernel_launch(void* const* d_in, const int* in_sizes, int n_in,
                              void* d_out, int out_size, void* d_ws, size_t ws_size,
                              hipStream_t stream) {
  const float* X  = (const float*)d_in[0];
  const int* QW   = (const int*)d_in[1];
  const int* QZ   = (const int*)d_in[2];
  const float* SC = (const float*)d_in[3];
  float* OUT      = (float*)d_out;
  _Float16* X16   = (_Float16*)d_ws;   // 32 MiB

  convert_x<<<dim3((M_DIM * (size_t)K_DIM / 8) / 256), 256, 0, stream>>>(X, X16);
  dim3 grid(N_DIM / 256, M_DIM / 256);
  gptq_gemm<<<grid, 512, 0, stream>>>(X16, QW, QZ, SC, OUT);
}